// Round 1
// baseline (272.098 us; speedup 1.0000x reference)
//
#include <hip/hip_runtime.h>
#include <math.h>

#define VOCAB 50257
#define DIM 768
#define RANK 16
#define SCALING 2.0f   // ALPHA / RANK = 32/16

constexpr int P1_BLOCKS = 2048;
constexpr int P1_THREADS = 192;                                    // 3 waves; each thread owns 4 columns
constexpr int ROWS_PER_BLOCK = (VOCAB + P1_BLOCKS - 1) / P1_BLOCKS; // 25
constexpr int RED_THREADS = 256;
constexpr int TOKENS_PER_BLOCK = 8;
constexpr int G_THREADS = 192;

// ---------------- Pass 1: per-block partial column sum-of-squares ----------------
// partials layout: [P1_BLOCKS][DIM] row-major. Every slot written (zeros for empty blocks),
// so no zero-init of workspace is required.
__global__ __launch_bounds__(P1_THREADS) void dora_pass1(
    const float* __restrict__ emb, const float* __restrict__ lora_a,
    const float* __restrict__ lora_b, float* __restrict__ partials) {
  const int t = threadIdx.x;     // 0..191
  const int c4 = t * 4;          // base column of this thread's float4 group

  // B[:, c4..c4+3] in registers: 16 x float4 = 64 VGPRs
  float4 B[RANK];
#pragma unroll
  for (int k = 0; k < RANK; ++k)
    B[k] = *reinterpret_cast<const float4*>(lora_b + k * DIM + c4);

  const int r0 = blockIdx.x * ROWS_PER_BLOCK;
  const int r1 = min(r0 + ROWS_PER_BLOCK, VOCAB);

  float4 acc = make_float4(0.f, 0.f, 0.f, 0.f);
  for (int v = r0; v < r1; ++v) {
    // A row: address is wave-uniform -> compiler emits scalar loads (SGPR broadcast)
    const float* __restrict__ arow = lora_a + (size_t)v * RANK;
    const float4 e = *reinterpret_cast<const float4*>(emb + (size_t)v * DIM + c4);
    float dx = 0.f, dy = 0.f, dz = 0.f, dw = 0.f;
#pragma unroll
    for (int k = 0; k < RANK; ++k) {
      const float a = arow[k];
      dx = fmaf(a, B[k].x, dx);
      dy = fmaf(a, B[k].y, dy);
      dz = fmaf(a, B[k].z, dz);
      dw = fmaf(a, B[k].w, dw);
    }
    const float cx = fmaf(SCALING, dx, e.x);
    const float cy = fmaf(SCALING, dy, e.y);
    const float cz = fmaf(SCALING, dz, e.z);
    const float cw = fmaf(SCALING, dw, e.w);
    acc.x = fmaf(cx, cx, acc.x);
    acc.y = fmaf(cy, cy, acc.y);
    acc.z = fmaf(cz, cz, acc.z);
    acc.w = fmaf(cw, cw, acc.w);
  }
  *reinterpret_cast<float4*>(partials + (size_t)blockIdx.x * DIM + c4) = acc;
}

// ---------------- Reduce: one block per column -> scale[d] = mag[d]/max(norm,1e-8) ----------------
__global__ __launch_bounds__(RED_THREADS) void dora_reduce(
    const float* __restrict__ partials, const float* __restrict__ magnitude,
    float* __restrict__ scale) {
  const int c = blockIdx.x;    // 0..767
  const int t = threadIdx.x;   // 0..255
  float s = 0.f;
#pragma unroll
  for (int k = 0; k < P1_BLOCKS / RED_THREADS; ++k)
    s += partials[(size_t)(t + k * RED_THREADS) * DIM + c];

  // wave (64-lane) butterfly, then cross-wave via LDS
#pragma unroll
  for (int off = 32; off > 0; off >>= 1) s += __shfl_down(s, off);

  __shared__ float lds[RED_THREADS / 64];
  if ((t & 63) == 0) lds[t >> 6] = s;
  __syncthreads();
  if (t == 0) {
    float tot = 0.f;
#pragma unroll
    for (int w = 0; w < RED_THREADS / 64; ++w) tot += lds[w];
    const float norm = fmaxf(sqrtf(tot), 1e-8f);
    scale[c] = magnitude[c] / norm;
  }
}

// ---------------- Gather: 8 tokens per block, B reused in registers ----------------
__global__ __launch_bounds__(G_THREADS) void dora_gather(
    const int* __restrict__ tokens, const float* __restrict__ emb,
    const float* __restrict__ lora_a, const float* __restrict__ lora_b,
    const float* __restrict__ scale, float* __restrict__ out, int n_tokens) {
  const int t = threadIdx.x;
  const int c4 = t * 4;

  float4 B[RANK];
#pragma unroll
  for (int k = 0; k < RANK; ++k)
    B[k] = *reinterpret_cast<const float4*>(lora_b + k * DIM + c4);
  const float4 sc = *reinterpret_cast<const float4*>(scale + c4);

  const int tok0 = blockIdx.x * TOKENS_PER_BLOCK;
#pragma unroll
  for (int i = 0; i < TOKENS_PER_BLOCK; ++i) {
    const int tok = tok0 + i;
    if (tok >= n_tokens) break;
    const int id = tokens[tok];                          // wave-uniform
    const float* __restrict__ arow = lora_a + (size_t)id * RANK;  // scalar loads
    const float4 e = *reinterpret_cast<const float4*>(emb + (size_t)id * DIM + c4);
    float dx = 0.f, dy = 0.f, dz = 0.f, dw = 0.f;
#pragma unroll
    for (int k = 0; k < RANK; ++k) {
      const float a = arow[k];
      dx = fmaf(a, B[k].x, dx);
      dy = fmaf(a, B[k].y, dy);
      dz = fmaf(a, B[k].z, dz);
      dw = fmaf(a, B[k].w, dw);
    }
    float4 o;
    o.x = fmaf(SCALING, dx, e.x) * sc.x;
    o.y = fmaf(SCALING, dy, e.y) * sc.y;
    o.z = fmaf(SCALING, dz, e.z) * sc.z;
    o.w = fmaf(SCALING, dw, e.w) * sc.w;
    *reinterpret_cast<float4*>(out + (size_t)tok * DIM + c4) = o;
  }
}

extern "C" void kernel_launch(void* const* d_in, const int* in_sizes, int n_in,
                              void* d_out, int out_size, void* d_ws, size_t ws_size,
                              hipStream_t stream) {
  const int*   tokens    = (const int*)d_in[0];    // [8,2048] int32
  const float* emb       = (const float*)d_in[1];  // [V, D]
  const float* lora_a    = (const float*)d_in[2];  // [V, R]
  const float* lora_b    = (const float*)d_in[3];  // [R, D]
  const float* magnitude = (const float*)d_in[4];  // [D]
  float* out = (float*)d_out;

  const int n_tokens = in_sizes[0];                // 16384

  float* partials = (float*)d_ws;                                  // P1_BLOCKS * DIM floats
  float* scale    = (float*)d_ws + (size_t)P1_BLOCKS * DIM;        // DIM floats

  dora_pass1<<<P1_BLOCKS, P1_THREADS, 0, stream>>>(emb, lora_a, lora_b, partials);
  dora_reduce<<<DIM, RED_THREADS, 0, stream>>>(partials, magnitude, scale);

  const int gather_blocks = (n_tokens + TOKENS_PER_BLOCK - 1) / TOKENS_PER_BLOCK;
  dora_gather<<<gather_blocks, G_THREADS, 0, stream>>>(tokens, emb, lora_a, lora_b,
                                                       scale, out, n_tokens);
}